// Round 10
// baseline (574.332 us; speedup 1.0000x reference)
//
#include <hip/hip_runtime.h>

#define NH   8192
#define DIM  256
#define NTOT 16384
#define TILE 256
#define NB   64                   // NTOT / TILE
#define NTRI (NB * (NB + 1) / 2)  // 2080
#define TRIOFF(x) ((x) * (2 * NB + 1 - (x)) / 2)  // x*(129-x)/2

constexpr float GAMMA = 0.00390625f; // 1/256

using short4v = __attribute__((ext_vector_type(4))) short;
using half8   = __attribute__((ext_vector_type(8))) _Float16;
using f32x4   = __attribute__((ext_vector_type(4))) float;

// ---------------- fused convert (fp32 -> f16) + exact fp32 row norms ----------------
__global__ void prep_kernel(const float* __restrict__ zs,
                            const float* __restrict__ zt,
                            unsigned short* __restrict__ Zf,
                            float* __restrict__ n2) {
    int w = threadIdx.x >> 6, l = threadIdx.x & 63;
    int row = blockIdx.x * 4 + w;
    const float* zp = (row < NH) ? zs + (size_t)row * DIM
                                 : zt + (size_t)(row - NH) * DIM;
    float4 v = *(const float4*)(zp + l * 4);
    float s = v.x * v.x + v.y * v.y + v.z * v.z + v.w * v.w;
#pragma unroll
    for (int off = 32; off; off >>= 1) s += __shfl_xor(s, off);
    if (l == 0) n2[row] = s;

    float x[4] = {v.x, v.y, v.z, v.w};
    short4v hv;
#pragma unroll
    for (int j = 0; j < 4; ++j) {
        _Float16 h = (_Float16)x[j];          // RNE
        hv[j] = *(short*)&h;
    }
    *(short4v*)(Zf + (size_t)row * DIM + l * 4) = hv;
}

// ---------------- main: 256x256 tiles, 8 waves, f16 MFMA ----------------
// 2-buffer LDS (64 KB -> 2 blocks/CU), depth-1 prefetch, counted vmcnt + raw s_barrier
__global__ __launch_bounds__(512, 4)
void mmd_mfma_kernel(const unsigned short* __restrict__ Zf,
                     const float* __restrict__ n2,
                     double* __restrict__ partial) {
    // 2 buffers x {A 256x32, B 256x32} f16 = 2 x 32 KB = 64 KB
    __shared__ __align__(16) unsigned short lds[2][16384];

    const int tid = threadIdx.x;
    const int w = tid >> 6, l = tid & 63;
    const int wr = w >> 2, wc = w & 3;   // 2x4 wave grid; wave owns 128x64
    const int fr = l & 15;               // fragment row/col within 16
    const int g  = l >> 4;               // k-group 0..3

    // XCD-aware bijective swizzle (2080 % 8 == 0)
    int t = ((int)blockIdx.x & 7) * (NTRI / 8) + ((int)blockIdx.x >> 3);

    // linear t -> upper-triangle (r, c), r <= c
    int r = (int)((129.0 - sqrt(129.0 * 129.0 - 8.0 * (double)t)) * 0.5);
    if (r < 0) r = 0;
    if (r > NB - 1) r = NB - 1;
    while (r < NB - 1 && TRIOFF(r + 1) <= t) ++r;
    while (r > 0 && TRIOFF(r) > t) --r;
    const int c = r + (t - TRIOFF(r));
    const int xbase = r * TILE, ybase = c * TILE;

    const unsigned short* gA = Zf + (size_t)xbase * DIM;
    const unsigned short* gB = Zf + (size_t)ybase * DIM;

    // fragment reads: slot' = g ^ ((fr>>1)&3)   (verified conflict-free R2/R3/R6/R7/R9)
    const int slotp = g ^ ((fr >> 1) & 3);
    const int aoff = (wr * 128 + fr) * 32 + slotp * 8;           // + m*512
    const int boff = 8192 + (wc * 64 + fr) * 32 + slotp * 8;     // + n*512

    f32x4 acc[8][4];
#pragma unroll
    for (int m = 0; m < 8; ++m)
#pragma unroll
        for (int n = 0; n < 4; ++n) acc[m][n] = {0.f, 0.f, 0.f, 0.f};

    // staging: linear LDS dest, pre-swizzled global source slot
    // 4 global_load_lds per thread per STAGE (A: 2, B: 2); 512 threads
#define STAGE(KC, P)                                                                 \
    {                                                                                \
        _Pragma("unroll")                                                            \
        for (int q = 0; q < 2; ++q) { /* A: 1024 x 16B */                            \
            const int idx = q * 512 + tid;                                           \
            const int row = idx >> 2;                                                \
            const int slot = (idx & 3) ^ ((row >> 1) & 3);                           \
            const unsigned short* src = gA + (size_t)row * DIM + (KC) + slot * 8;    \
            __builtin_amdgcn_global_load_lds(src, &lds[P][idx * 8], 16, 0, 0);       \
        }                                                                            \
        _Pragma("unroll")                                                            \
        for (int q = 0; q < 2; ++q) { /* B: 1024 x 16B */                            \
            const int idx = q * 512 + tid;                                           \
            const int row = idx >> 2;                                                \
            const int slot = (idx & 3) ^ ((row >> 1) & 3);                           \
            const unsigned short* src = gB + (size_t)row * DIM + (KC) + slot * 8;    \
            __builtin_amdgcn_global_load_lds(src, &lds[P][8192 + idx * 8], 16, 0, 0);\
        }                                                                            \
    }

    STAGE(0, 0);

    for (int ch = 0; ch < 8; ++ch) {
        const int p = ch & 1;
        if (ch < 7) {
            STAGE((ch + 1) * 32, p ^ 1);  // next chunk in flight across this chunk
            asm volatile("s_waitcnt vmcnt(4)" ::: "memory");  // chunk ch landed; ch+1's 4 in flight
        } else {
            asm volatile("s_waitcnt vmcnt(0)" ::: "memory");
        }
        __builtin_amdgcn_s_barrier();  // all waves' chunk-ch data resident

        half8 bq[4];
#pragma unroll
        for (int n = 0; n < 4; ++n) bq[n] = *(const half8*)&lds[p][boff + n * 512];
        __builtin_amdgcn_s_setprio(1);
#pragma unroll
        for (int m = 0; m < 8; ++m) {
            half8 aq = *(const half8*)&lds[p][aoff + m * 512];
#pragma unroll
            for (int n = 0; n < 4; ++n)
                acc[m][n] = __builtin_amdgcn_mfma_f32_16x16x32_f16(aq, bq[n], acc[m][n], 0, 0, 0);
        }
        __builtin_amdgcn_s_setprio(0);
        __builtin_amdgcn_s_barrier();  // all waves done reading lds[p] before its rewrite
    }

    // epilogue: exp(-g*d2) = exp2(K2*dot - cx - cy);  __builtin_amdgcn_exp2f -> v_exp_f32
    // C/D layout: col = lane&15 (fr), row = (lane>>4)*4 + reg   (verified R2..R9)
    const float GL = GAMMA * 1.4426950408889634f;  // gamma*log2(e)
    const float K2 = 2.0f * GL;
    float ncy[4];
    int   gjs[4];
#pragma unroll
    for (int n = 0; n < 4; ++n) {
        gjs[n] = ybase + wc * 64 + n * 16 + fr;
        ncy[n] = -GL * n2[gjs[n]];
    }
    float fsum;
    if (r != c) {  // strictly above diagonal: uniform weight 2
        float fs0 = 0.f, fs1 = 0.f, fs2 = 0.f, fs3 = 0.f;  // break serial add chain
#pragma unroll
        for (int m = 0; m < 8; ++m) {
#pragma unroll
            for (int j = 0; j < 4; ++j) {
                float cx = GL * n2[xbase + wr * 128 + m * 16 + g * 4 + j];
                fs0 += __builtin_amdgcn_exp2f(fmaf(K2, acc[m][0][j], ncy[0]) - cx);
                fs1 += __builtin_amdgcn_exp2f(fmaf(K2, acc[m][1][j], ncy[1]) - cx);
                fs2 += __builtin_amdgcn_exp2f(fmaf(K2, acc[m][2][j], ncy[2]) - cx);
                fs3 += __builtin_amdgcn_exp2f(fmaf(K2, acc[m][3][j], ncy[3]) - cx);
            }
        }
        fsum = ((fs0 + fs1) + (fs2 + fs3)) * 2.0f;
    } else {  // diagonal tile: i<j -> 2, i==j -> 1, i>j -> 0
        fsum = 0.f;
#pragma unroll
        for (int m = 0; m < 8; ++m) {
#pragma unroll
            for (int j = 0; j < 4; ++j) {
                const int gi = xbase + wr * 128 + m * 16 + g * 4 + j;
                float cx = GL * n2[gi];
#pragma unroll
                for (int n = 0; n < 4; ++n) {
                    float e = __builtin_amdgcn_exp2f(fmaf(K2, acc[m][n][j], ncy[n]) - cx);
                    float wgt = (gi < gjs[n]) ? 2.0f : ((gi == gjs[n]) ? 1.0f : 0.0f);
                    fsum += wgt * e;
                }
            }
        }
    }

#pragma unroll
    for (int off = 32; off; off >>= 1) fsum += __shfl_xor(fsum, off);

    __syncthreads();
    double* wsum = (double*)&lds[0][0];
    if (l == 0) wsum[w] = (double)fsum;
    __syncthreads();
    if (tid == 0) {
        double tot = 0.0;
#pragma unroll
        for (int i = 0; i < 8; ++i) tot += wsum[i];
        double sgn = ((xbase < NH) == (ybase < NH)) ? 1.0 : -1.0;
        partial[blockIdx.x] = sgn * tot;
    }
}

// ---------------- final reduce ----------------
__global__ void reduce_partials_kernel(const double* __restrict__ partial,
                                       float* __restrict__ out) {
    __shared__ double ws[4];
    double s = 0.0;
    for (int i = threadIdx.x; i < NTRI; i += 256) s += partial[i];
#pragma unroll
    for (int off = 32; off; off >>= 1) s += __shfl_xor(s, off);
    if ((threadIdx.x & 63) == 0) ws[threadIdx.x >> 6] = s;
    __syncthreads();
    if (threadIdx.x == 0) {
        double tot = ws[0] + ws[1] + ws[2] + ws[3];
        out[0] = (float)(tot / ((double)NH * (double)NH));
    }
}

extern "C" void kernel_launch(void* const* d_in, const int* in_sizes, int n_in,
                              void* d_out, int out_size, void* d_ws, size_t ws_size,
                              hipStream_t stream) {
    const float* zs = (const float*)d_in[0];
    const float* zt = (const float*)d_in[1];
    float* out = (float*)d_out;

    unsigned short* Zf = (unsigned short*)d_ws;                  // 8 MB (f16)
    float*  n2      = (float*)((char*)d_ws + 8388608);           // 64 KB
    double* partial = (double*)((char*)d_ws + 8454144);          // 17 KB

    prep_kernel<<<NTOT / 4, 256, 0, stream>>>(zs, zt, Zf, n2);
    mmd_mfma_kernel<<<NTRI, 512, 0, stream>>>(Zf, n2, partial);
    reduce_partials_kernel<<<1, 256, 0, stream>>>(partial, out);
}

// Round 11
// 107.596 us; speedup vs baseline: 5.3379x; 5.3379x over previous
//
#include <hip/hip_runtime.h>

#define NH   8192
#define DIM  256
#define NTOT 16384
#define TILE 256
#define NB   64                   // NTOT / TILE
#define NTRI (NB * (NB + 1) / 2)  // 2080
#define TRIOFF(x) ((x) * (2 * NB + 1 - (x)) / 2)  // x*(129-x)/2

constexpr float GAMMA = 0.00390625f; // 1/256

using short4v = __attribute__((ext_vector_type(4))) short;
using half8   = __attribute__((ext_vector_type(8))) _Float16;
using f32x4   = __attribute__((ext_vector_type(4))) float;

// ---------------- fused convert (fp32 -> f16) + exact fp32 row norms ----------------
__global__ void prep_kernel(const float* __restrict__ zs,
                            const float* __restrict__ zt,
                            unsigned short* __restrict__ Zf,
                            float* __restrict__ n2) {
    int w = threadIdx.x >> 6, l = threadIdx.x & 63;
    int row = blockIdx.x * 4 + w;
    const float* zp = (row < NH) ? zs + (size_t)row * DIM
                                 : zt + (size_t)(row - NH) * DIM;
    float4 v = *(const float4*)(zp + l * 4);
    float s = v.x * v.x + v.y * v.y + v.z * v.z + v.w * v.w;
#pragma unroll
    for (int off = 32; off; off >>= 1) s += __shfl_xor(s, off);
    if (l == 0) n2[row] = s;

    float x[4] = {v.x, v.y, v.z, v.w};
    short4v hv;
#pragma unroll
    for (int j = 0; j < 4; ++j) {
        _Float16 h = (_Float16)x[j];          // RNE
        hv[j] = *(short*)&h;
    }
    *(short4v*)(Zf + (size_t)row * DIM + l * 4) = hv;
}

// ---------------- main: 256x256 tiles, 8 waves, f16 MFMA ----------------
// 2-buffer LDS (64 KB -> 2 blocks/CU), depth-1 prefetch, counted vmcnt + raw s_barrier
// launch_bounds(512,2): VGPR cap 256 — (512,4) capped at 128 and spilled acc (R10, 1.6 GB scratch)
__global__ __launch_bounds__(512, 2)
void mmd_mfma_kernel(const unsigned short* __restrict__ Zf,
                     const float* __restrict__ n2,
                     double* __restrict__ partial) {
    // 2 buffers x {A 256x32, B 256x32} f16 = 2 x 32 KB = 64 KB
    __shared__ __align__(16) unsigned short lds[2][16384];

    const int tid = threadIdx.x;
    const int w = tid >> 6, l = tid & 63;
    const int wr = w >> 2, wc = w & 3;   // 2x4 wave grid; wave owns 128x64
    const int fr = l & 15;               // fragment row/col within 16
    const int g  = l >> 4;               // k-group 0..3

    // XCD-aware bijective swizzle (2080 % 8 == 0)
    int t = ((int)blockIdx.x & 7) * (NTRI / 8) + ((int)blockIdx.x >> 3);

    // linear t -> upper-triangle (r, c), r <= c
    int r = (int)((129.0 - sqrt(129.0 * 129.0 - 8.0 * (double)t)) * 0.5);
    if (r < 0) r = 0;
    if (r > NB - 1) r = NB - 1;
    while (r < NB - 1 && TRIOFF(r + 1) <= t) ++r;
    while (r > 0 && TRIOFF(r) > t) --r;
    const int c = r + (t - TRIOFF(r));
    const int xbase = r * TILE, ybase = c * TILE;

    const unsigned short* gA = Zf + (size_t)xbase * DIM;
    const unsigned short* gB = Zf + (size_t)ybase * DIM;

    // fragment reads: slot' = g ^ ((fr>>1)&3)   (verified conflict-free R2/R3/R6/R7/R9)
    const int slotp = g ^ ((fr >> 1) & 3);
    const int aoff = (wr * 128 + fr) * 32 + slotp * 8;           // + m*512
    const int boff = 8192 + (wc * 64 + fr) * 32 + slotp * 8;     // + n*512

    f32x4 acc[8][4];
#pragma unroll
    for (int m = 0; m < 8; ++m)
#pragma unroll
        for (int n = 0; n < 4; ++n) acc[m][n] = {0.f, 0.f, 0.f, 0.f};

    // staging: linear LDS dest, pre-swizzled global source slot
    // 4 global_load_lds per thread per STAGE (A: 2, B: 2); 512 threads
#define STAGE(KC, P)                                                                 \
    {                                                                                \
        _Pragma("unroll")                                                            \
        for (int q = 0; q < 2; ++q) { /* A: 1024 x 16B */                            \
            const int idx = q * 512 + tid;                                           \
            const int row = idx >> 2;                                                \
            const int slot = (idx & 3) ^ ((row >> 1) & 3);                           \
            const unsigned short* src = gA + (size_t)row * DIM + (KC) + slot * 8;    \
            __builtin_amdgcn_global_load_lds(src, &lds[P][idx * 8], 16, 0, 0);       \
        }                                                                            \
        _Pragma("unroll")                                                            \
        for (int q = 0; q < 2; ++q) { /* B: 1024 x 16B */                            \
            const int idx = q * 512 + tid;                                           \
            const int row = idx >> 2;                                                \
            const int slot = (idx & 3) ^ ((row >> 1) & 3);                           \
            const unsigned short* src = gB + (size_t)row * DIM + (KC) + slot * 8;    \
            __builtin_amdgcn_global_load_lds(src, &lds[P][8192 + idx * 8], 16, 0, 0);\
        }                                                                            \
    }

    STAGE(0, 0);

    for (int ch = 0; ch < 8; ++ch) {
        const int p = ch & 1;
        if (ch < 7) {
            STAGE((ch + 1) * 32, p ^ 1);  // next chunk in flight across this chunk
            asm volatile("s_waitcnt vmcnt(4)" ::: "memory");  // chunk ch landed; ch+1's 4 in flight
        } else {
            asm volatile("s_waitcnt vmcnt(0)" ::: "memory");
        }
        __builtin_amdgcn_s_barrier();  // all waves' chunk-ch data resident

        half8 bq[4];
#pragma unroll
        for (int n = 0; n < 4; ++n) bq[n] = *(const half8*)&lds[p][boff + n * 512];
        __builtin_amdgcn_s_setprio(1);
#pragma unroll
        for (int m = 0; m < 8; ++m) {
            half8 aq = *(const half8*)&lds[p][aoff + m * 512];
#pragma unroll
            for (int n = 0; n < 4; ++n)
                acc[m][n] = __builtin_amdgcn_mfma_f32_16x16x32_f16(aq, bq[n], acc[m][n], 0, 0, 0);
        }
        __builtin_amdgcn_s_setprio(0);
        __builtin_amdgcn_s_barrier();  // all waves done reading lds[p] before its rewrite
    }

    // epilogue: exp(-g*d2) = exp2(K2*dot - cx - cy);  __builtin_amdgcn_exp2f -> v_exp_f32
    // C/D layout: col = lane&15 (fr), row = (lane>>4)*4 + reg   (verified R2..R9)
    const float GL = GAMMA * 1.4426950408889634f;  // gamma*log2(e)
    const float K2 = 2.0f * GL;
    float ncy[4];
    int   gjs[4];
#pragma unroll
    for (int n = 0; n < 4; ++n) {
        gjs[n] = ybase + wc * 64 + n * 16 + fr;
        ncy[n] = -GL * n2[gjs[n]];
    }
    float fsum;
    if (r != c) {  // strictly above diagonal: uniform weight 2
        float fs0 = 0.f, fs1 = 0.f, fs2 = 0.f, fs3 = 0.f;  // break serial add chain
#pragma unroll
        for (int m = 0; m < 8; ++m) {
#pragma unroll
            for (int j = 0; j < 4; ++j) {
                float cx = GL * n2[xbase + wr * 128 + m * 16 + g * 4 + j];
                fs0 += __builtin_amdgcn_exp2f(fmaf(K2, acc[m][0][j], ncy[0]) - cx);
                fs1 += __builtin_amdgcn_exp2f(fmaf(K2, acc[m][1][j], ncy[1]) - cx);
                fs2 += __builtin_amdgcn_exp2f(fmaf(K2, acc[m][2][j], ncy[2]) - cx);
                fs3 += __builtin_amdgcn_exp2f(fmaf(K2, acc[m][3][j], ncy[3]) - cx);
            }
        }
        fsum = ((fs0 + fs1) + (fs2 + fs3)) * 2.0f;
    } else {  // diagonal tile: i<j -> 2, i==j -> 1, i>j -> 0
        fsum = 0.f;
#pragma unroll
        for (int m = 0; m < 8; ++m) {
#pragma unroll
            for (int j = 0; j < 4; ++j) {
                const int gi = xbase + wr * 128 + m * 16 + g * 4 + j;
                float cx = GL * n2[gi];
#pragma unroll
                for (int n = 0; n < 4; ++n) {
                    float e = __builtin_amdgcn_exp2f(fmaf(K2, acc[m][n][j], ncy[n]) - cx);
                    float wgt = (gi < gjs[n]) ? 2.0f : ((gi == gjs[n]) ? 1.0f : 0.0f);
                    fsum += wgt * e;
                }
            }
        }
    }

#pragma unroll
    for (int off = 32; off; off >>= 1) fsum += __shfl_xor(fsum, off);

    __syncthreads();
    double* wsum = (double*)&lds[0][0];
    if (l == 0) wsum[w] = (double)fsum;
    __syncthreads();
    if (tid == 0) {
        double tot = 0.0;
#pragma unroll
        for (int i = 0; i < 8; ++i) tot += wsum[i];
        double sgn = ((xbase < NH) == (ybase < NH)) ? 1.0 : -1.0;
        partial[blockIdx.x] = sgn * tot;
    }
}

// ---------------- final reduce ----------------
__global__ void reduce_partials_kernel(const double* __restrict__ partial,
                                       float* __restrict__ out) {
    __shared__ double ws[4];
    double s = 0.0;
    for (int i = threadIdx.x; i < NTRI; i += 256) s += partial[i];
#pragma unroll
    for (int off = 32; off; off >>= 1) s += __shfl_xor(s, off);
    if ((threadIdx.x & 63) == 0) ws[threadIdx.x >> 6] = s;
    __syncthreads();
    if (threadIdx.x == 0) {
        double tot = ws[0] + ws[1] + ws[2] + ws[3];
        out[0] = (float)(tot / ((double)NH * (double)NH));
    }
}

extern "C" void kernel_launch(void* const* d_in, const int* in_sizes, int n_in,
                              void* d_out, int out_size, void* d_ws, size_t ws_size,
                              hipStream_t stream) {
    const float* zs = (const float*)d_in[0];
    const float* zt = (const float*)d_in[1];
    float* out = (float*)d_out;

    unsigned short* Zf = (unsigned short*)d_ws;                  // 8 MB (f16)
    float*  n2      = (float*)((char*)d_ws + 8388608);           // 64 KB
    double* partial = (double*)((char*)d_ws + 8454144);          // 17 KB

    prep_kernel<<<NTOT / 4, 256, 0, stream>>>(zs, zt, Zf, n2);
    mmd_mfma_kernel<<<NTRI, 512, 0, stream>>>(Zf, n2, partial);
    reduce_partials_kernel<<<1, 256, 0, stream>>>(partial, out);
}

// Round 12
// 105.321 us; speedup vs baseline: 5.4532x; 1.0216x over previous
//
#include <hip/hip_runtime.h>

#define NH   8192
#define DIM  256
#define NTOT 16384
#define TILE 256
#define NB   64                   // NTOT / TILE
#define NTRI (NB * (NB + 1) / 2)  // 2080
#define TRIOFF(x) ((x) * (2 * NB + 1 - (x)) / 2)  // x*(129-x)/2

constexpr float GAMMA = 0.00390625f; // 1/256

using short4v = __attribute__((ext_vector_type(4))) short;
using half8   = __attribute__((ext_vector_type(8))) _Float16;
using f32x4   = __attribute__((ext_vector_type(4))) float;

// ---------------- fused convert (fp32 -> f16) + exact fp32 row norms ----------------
__global__ void prep_kernel(const float* __restrict__ zs,
                            const float* __restrict__ zt,
                            unsigned short* __restrict__ Zf,
                            float* __restrict__ n2) {
    int w = threadIdx.x >> 6, l = threadIdx.x & 63;
    int row = blockIdx.x * 4 + w;
    const float* zp = (row < NH) ? zs + (size_t)row * DIM
                                 : zt + (size_t)(row - NH) * DIM;
    float4 v = *(const float4*)(zp + l * 4);
    float s = v.x * v.x + v.y * v.y + v.z * v.z + v.w * v.w;
#pragma unroll
    for (int off = 32; off; off >>= 1) s += __shfl_xor(s, off);
    if (l == 0) n2[row] = s;

    float x[4] = {v.x, v.y, v.z, v.w};
    short4v hv;
#pragma unroll
    for (int j = 0; j < 4; ++j) {
        _Float16 h = (_Float16)x[j];          // RNE
        hv[j] = *(short*)&h;
    }
    *(short4v*)(Zf + (size_t)row * DIM + l * 4) = hv;
}

// ---------------- main: 256x256 tiles, 8 waves, f16 MFMA, m201-style 4-phase/K-tile ----------------
// BK=64 (2x32 sub-chunks), 2x64KB LDS dbuf, staggered stage units, boundary vmcnt(2)
__global__ __launch_bounds__(512, 2)
void mmd_mfma_kernel(const unsigned short* __restrict__ Zf,
                     const float* __restrict__ n2,
                     double* __restrict__ partial) {
    // buffer layout (halves): [A h0: 8192][A h1: 8192][B h0: 8192][B h1: 8192] = 64 KB
    __shared__ __align__(16) unsigned short lds[2][32768];  // 128 KB total

    const int tid = threadIdx.x;
    const int w = tid >> 6, l = tid & 63;
    const int wr = w >> 2, wc = w & 3;   // 2x4 wave grid; wave owns 128x64
    const int fr = l & 15;               // fragment row/col within 16
    const int g  = l >> 4;               // k-group 0..3

    // XCD-aware bijective swizzle (2080 % 8 == 0)
    int t = ((int)blockIdx.x & 7) * (NTRI / 8) + ((int)blockIdx.x >> 3);

    // linear t -> upper-triangle (r, c), r <= c
    int r = (int)((129.0 - sqrt(129.0 * 129.0 - 8.0 * (double)t)) * 0.5);
    if (r < 0) r = 0;
    if (r > NB - 1) r = NB - 1;
    while (r < NB - 1 && TRIOFF(r + 1) <= t) ++r;
    while (r > 0 && TRIOFF(r) > t) --r;
    const int c = r + (t - TRIOFF(r));
    const int xbase = r * TILE, ybase = c * TILE;

    const unsigned short* gA = Zf + (size_t)xbase * DIM;
    const unsigned short* gB = Zf + (size_t)ybase * DIM;

    // fragment reads: slot' = g ^ ((fr>>1)&3)   (verified conflict-free R2..R11)
    const int slotp = g ^ ((fr >> 1) & 3);
    const int abase = (wr * 128 + fr) * 32 + slotp * 8;          // + ks*8192 + m*512
    const int bbase = 16384 + (wc * 64 + fr) * 32 + slotp * 8;   // + ks*8192 + n*512

    f32x4 acc[8][4];
#pragma unroll
    for (int m = 0; m < 8; ++m)
#pragma unroll
        for (int n = 0; n < 4; ++n) acc[m][n] = {0.f, 0.f, 0.f, 0.f};

    // stage unit = one 32-wide sub-chunk of A or B: 1024 x 16B, 2 loads/thread
#define STA(KT, H, P) do {                                                            \
        _Pragma("unroll")                                                             \
        for (int q = 0; q < 2; ++q) {                                                 \
            const int idx = q * 512 + tid;                                            \
            const int row = idx >> 2;                                                 \
            const int slot = (idx & 3) ^ ((row >> 1) & 3);                            \
            const unsigned short* src = gA + (size_t)row * DIM + (KT) * 64 + (H) * 32 + slot * 8; \
            __builtin_amdgcn_global_load_lds(src, &lds[P][(H) * 8192 + idx * 8], 16, 0, 0); \
        }                                                                             \
    } while (0)

#define STB(KT, H, P) do {                                                            \
        _Pragma("unroll")                                                             \
        for (int q = 0; q < 2; ++q) {                                                 \
            const int idx = q * 512 + tid;                                            \
            const int row = idx >> 2;                                                 \
            const int slot = (idx & 3) ^ ((row >> 1) & 3);                            \
            const unsigned short* src = gB + (size_t)row * DIM + (KT) * 64 + (H) * 32 + slot * 8; \
            __builtin_amdgcn_global_load_lds(src, &lds[P][16384 + (H) * 8192 + idx * 8], 16, 0, 0); \
        }                                                                             \
    } while (0)

    half8 bq[4];  // B fragments, live across phase pairs

    // phase: {ds_read A (4) [+ B (4) on MH==0]; issue stage unit; barrier; 16 MFMA; barrier}
#define PHASE(P, KS, MH, STG) do {                                                    \
        const unsigned short* Lp = &lds[P][0];                                        \
        half8 aq[4];                                                                  \
        _Pragma("unroll")                                                             \
        for (int m_ = 0; m_ < 4; ++m_)                                                \
            aq[m_] = *(const half8*)&Lp[(KS) * 8192 + abase + ((MH) * 4 + m_) * 512]; \
        if ((MH) == 0) {                                                              \
            _Pragma("unroll")                                                         \
            for (int n = 0; n < 4; ++n)                                               \
                bq[n] = *(const half8*)&Lp[(KS) * 8192 + bbase + n * 512];            \
        }                                                                             \
        STG;                                                                          \
        __builtin_amdgcn_s_barrier();                                                 \
        __builtin_amdgcn_s_setprio(1);                                                \
        _Pragma("unroll")                                                             \
        for (int m_ = 0; m_ < 4; ++m_) {                                              \
            _Pragma("unroll")                                                         \
            for (int n = 0; n < 4; ++n)                                               \
                acc[(MH) * 4 + m_][n] = __builtin_amdgcn_mfma_f32_16x16x32_f16(       \
                    aq[m_], bq[n], acc[(MH) * 4 + m_][n], 0, 0, 0);                   \
        }                                                                             \
        __builtin_amdgcn_s_setprio(0);                                                \
        __builtin_amdgcn_s_barrier();                                                 \
    } while (0)

#define BOUNDARY2(STG) do { STG;                                                      \
        asm volatile("s_waitcnt vmcnt(2)" ::: "memory");                              \
        __builtin_amdgcn_s_barrier(); } while (0)

    // prologue: kt0 complete (8 loads) + kt1's first unit (2) -> vmcnt(2)
    STA(0, 0, 0); STA(0, 1, 0); STB(0, 0, 0); STB(0, 1, 0);
    STA(1, 0, 1);
    asm volatile("s_waitcnt vmcnt(2)" ::: "memory");
    __builtin_amdgcn_s_barrier();

    // kt0 (buf 0); stage kt1 remainder into buf 1
    PHASE(0, 0, 0, STA(1, 1, 1));
    PHASE(0, 0, 1, STB(1, 0, 1));
    PHASE(0, 1, 0, STB(1, 1, 1));
    PHASE(0, 1, 1, ((void)0));
    BOUNDARY2(STA(2, 0, 0));          // kt2 unit0 into buf 0 (kt0 done reading)
    // kt1 (buf 1); stage kt2 remainder into buf 0
    PHASE(1, 0, 0, STA(2, 1, 0));
    PHASE(1, 0, 1, STB(2, 0, 0));
    PHASE(1, 1, 0, STB(2, 1, 0));
    PHASE(1, 1, 1, ((void)0));
    BOUNDARY2(STA(3, 0, 1));          // kt3 unit0 into buf 1
    // kt2 (buf 0); stage kt3 remainder into buf 1
    PHASE(0, 0, 0, STA(3, 1, 1));
    PHASE(0, 0, 1, STB(3, 0, 1));
    PHASE(0, 1, 0, STB(3, 1, 1));
    PHASE(0, 1, 1, ((void)0));
    asm volatile("s_waitcnt vmcnt(0)" ::: "memory");   // final boundary: drain
    __builtin_amdgcn_s_barrier();
    // kt3 (buf 1); no staging
    PHASE(1, 0, 0, ((void)0));
    PHASE(1, 0, 1, ((void)0));
    PHASE(1, 1, 0, ((void)0));
    PHASE(1, 1, 1, ((void)0));

    // epilogue: exp(-g*d2) = exp2(K2*dot - cx - cy);  __builtin_amdgcn_exp2f -> v_exp_f32
    // C/D layout: col = lane&15 (fr), row = (lane>>4)*4 + reg   (verified R2..R11)
    const float GL = GAMMA * 1.4426950408889634f;  // gamma*log2(e)
    const float K2 = 2.0f * GL;
    float ncy[4];
    int   gjs[4];
#pragma unroll
    for (int n = 0; n < 4; ++n) {
        gjs[n] = ybase + wc * 64 + n * 16 + fr;
        ncy[n] = -GL * n2[gjs[n]];
    }
    float fsum;
    if (r != c) {  // strictly above diagonal: uniform weight 2
        float fs0 = 0.f, fs1 = 0.f, fs2 = 0.f, fs3 = 0.f;  // break serial add chain
#pragma unroll
        for (int m = 0; m < 8; ++m) {
#pragma unroll
            for (int j = 0; j < 4; ++j) {
                float cx = GL * n2[xbase + wr * 128 + m * 16 + g * 4 + j];
                fs0 += __builtin_amdgcn_exp2f(fmaf(K2, acc[m][0][j], ncy[0]) - cx);
                fs1 += __builtin_amdgcn_exp2f(fmaf(K2, acc[m][1][j], ncy[1]) - cx);
                fs2 += __builtin_amdgcn_exp2f(fmaf(K2, acc[m][2][j], ncy[2]) - cx);
                fs3 += __builtin_amdgcn_exp2f(fmaf(K2, acc[m][3][j], ncy[3]) - cx);
            }
        }
        fsum = ((fs0 + fs1) + (fs2 + fs3)) * 2.0f;
    } else {  // diagonal tile: i<j -> 2, i==j -> 1, i>j -> 0
        fsum = 0.f;
#pragma unroll
        for (int m = 0; m < 8; ++m) {
#pragma unroll
            for (int j = 0; j < 4; ++j) {
                const int gi = xbase + wr * 128 + m * 16 + g * 4 + j;
                float cx = GL * n2[gi];
#pragma unroll
                for (int n = 0; n < 4; ++n) {
                    float e = __builtin_amdgcn_exp2f(fmaf(K2, acc[m][n][j], ncy[n]) - cx);
                    float wgt = (gi < gjs[n]) ? 2.0f : ((gi == gjs[n]) ? 1.0f : 0.0f);
                    fsum += wgt * e;
                }
            }
        }
    }

#pragma unroll
    for (int off = 32; off; off >>= 1) fsum += __shfl_xor(fsum, off);

    __syncthreads();
    double* wsum = (double*)&lds[0][0];
    if (l == 0) wsum[w] = (double)fsum;
    __syncthreads();
    if (tid == 0) {
        double tot = 0.0;
#pragma unroll
        for (int i = 0; i < 8; ++i) tot += wsum[i];
        double sgn = ((xbase < NH) == (ybase < NH)) ? 1.0 : -1.0;
        partial[blockIdx.x] = sgn * tot;
    }
}

// ---------------- final reduce ----------------
__global__ void reduce_partials_kernel(const double* __restrict__ partial,
                                       float* __restrict__ out) {
    __shared__ double ws[4];
    double s = 0.0;
    for (int i = threadIdx.x; i < NTRI; i += 256) s += partial[i];
#pragma unroll
    for (int off = 32; off; off >>= 1) s += __shfl_xor(s, off);
    if ((threadIdx.x & 63) == 0) ws[threadIdx.x >> 6] = s;
    __syncthreads();
    if (threadIdx.x == 0) {
        double tot = ws[0] + ws[1] + ws[2] + ws[3];
        out[0] = (float)(tot / ((double)NH * (double)NH));
    }
}

extern "C" void kernel_launch(void* const* d_in, const int* in_sizes, int n_in,
                              void* d_out, int out_size, void* d_ws, size_t ws_size,
                              hipStream_t stream) {
    const float* zs = (const float*)d_in[0];
    const float* zt = (const float*)d_in[1];
    float* out = (float*)d_out;

    unsigned short* Zf = (unsigned short*)d_ws;                  // 8 MB (f16)
    float*  n2      = (float*)((char*)d_ws + 8388608);           // 64 KB
    double* partial = (double*)((char*)d_ws + 8454144);          // 17 KB

    prep_kernel<<<NTOT / 4, 256, 0, stream>>>(zs, zt, Zf, n2);
    mmd_mfma_kernel<<<NTRI, 512, 0, stream>>>(Zf, n2, partial);
    reduce_partials_kernel<<<1, 256, 0, stream>>>(partial, out);
}

// Round 13
// 104.688 us; speedup vs baseline: 5.4861x; 1.0060x over previous
//
#include <hip/hip_runtime.h>

#define NH   8192
#define DIM  256
#define NTOT 16384
#define TILE 256
#define NB   64                   // NTOT / TILE
#define NTRI 2080                 // NB*(NB+1)/2
#define TBASE(R) ((R) * NB - (R) * ((R) - 1) / 2)  // row-major triangle base

constexpr float GAMMA = 0.00390625f; // 1/256

using short4v = __attribute__((ext_vector_type(4))) short;
using half8   = __attribute__((ext_vector_type(8))) _Float16;
using f32x4   = __attribute__((ext_vector_type(4))) float;

// ---------------- fused convert (fp32 -> f16) + exact fp32 row norms ----------------
__global__ void prep_kernel(const float* __restrict__ zs,
                            const float* __restrict__ zt,
                            unsigned short* __restrict__ Zf,
                            float* __restrict__ n2) {
    int w = threadIdx.x >> 6, l = threadIdx.x & 63;
    int row = blockIdx.x * 4 + w;
    const float* zp = (row < NH) ? zs + (size_t)row * DIM
                                 : zt + (size_t)(row - NH) * DIM;
    float4 v = *(const float4*)(zp + l * 4);
    float s = v.x * v.x + v.y * v.y + v.z * v.z + v.w * v.w;
#pragma unroll
    for (int off = 32; off; off >>= 1) s += __shfl_xor(s, off);
    if (l == 0) n2[row] = s;

    float x[4] = {v.x, v.y, v.z, v.w};
    short4v hv;
#pragma unroll
    for (int j = 0; j < 4; ++j) {
        _Float16 h = (_Float16)x[j];          // RNE
        hv[j] = *(short*)&h;
    }
    *(short4v*)(Zf + (size_t)row * DIM + l * 4) = hv;
}

// ---------------- main: persistent blocks, A row-panel resident in LDS ----------------
// grid 256 x 512 thr; each block streams ~8 triangle tiles (row-major), A staged once/row,
// B double-buffered, stage stream continuous across tiles, counted vmcnt(2).
__global__ __launch_bounds__(512, 2)
void mmd_mfma_kernel(const unsigned short* __restrict__ Zf,
                     const float* __restrict__ n2,
                     double* __restrict__ partial) {
    // [A panel: 8 chunks x 8192 halves = 128 KB][B dbuf: 2 x 8192 halves = 32 KB] = 160 KB
    __shared__ __align__(16) unsigned short lds[81920];

    const int tid = threadIdx.x;
    const int w = tid >> 6, l = tid & 63;
    const int wr = w >> 2, wc = w & 3;   // 2x4 wave grid; wave owns 128x64
    const int fr = l & 15;               // fragment row/col within 16
    const int g  = l >> 4;               // k-group 0..3

    // XCD swizzle on block id (256 % 8 == 0); sb indexes the tile-range partition
    const int sb = ((int)blockIdx.x & 7) * 32 + ((int)blockIdx.x >> 3);
    const int start = (NTRI * sb) >> 8;
    const int end   = (NTRI * (sb + 1)) >> 8;

    // first tile (R, C), row-major triangle
    int R = 0;
    while (R < NB - 1 && TBASE(R + 1) <= start) ++R;
    int C = R + (start - TBASE(R));

    // fragment read offsets: slot' = g ^ ((fr>>1)&3)   (verified conflict-free R2..R12)
    const int slotp = g ^ ((fr >> 1) & 3);
    const int aoff = (wr * 128 + fr) * 32 + slotp * 8;   // + ch*8192 + m*512
    const int boff = (wc * 64 + fr) * 32 + slotp * 8;    // + 65536 + pb*8192 + n*512

#define STAGE_A(GA) do {                                                              \
        _Pragma("unroll")                                                             \
        for (int ch_ = 0; ch_ < 8; ++ch_) {                                           \
            _Pragma("unroll")                                                         \
            for (int q_ = 0; q_ < 2; ++q_) {                                          \
                const int idx = q_ * 512 + tid;                                       \
                const int row_ = idx >> 2;                                            \
                const int slot_ = (idx & 3) ^ ((row_ >> 1) & 3);                      \
                const unsigned short* src = (GA) + (size_t)row_ * DIM + ch_ * 32 + slot_ * 8; \
                __builtin_amdgcn_global_load_lds(src, &lds[ch_ * 8192 + idx * 8], 16, 0, 0);  \
            }                                                                         \
        }                                                                             \
    } while (0)

#define STB(GB, CH, PB) do {                                                          \
        _Pragma("unroll")                                                             \
        for (int q_ = 0; q_ < 2; ++q_) {                                              \
            const int idx = q_ * 512 + tid;                                           \
            const int row_ = idx >> 2;                                                \
            const int slot_ = (idx & 3) ^ ((row_ >> 1) & 3);                          \
            const unsigned short* src = (GB) + (size_t)row_ * DIM + (CH) * 32 + slot_ * 8; \
            __builtin_amdgcn_global_load_lds(src, &lds[65536 + (PB) * 8192 + idx * 8], 16, 0, 0); \
        }                                                                             \
    } while (0)

    const float GL = GAMMA * 1.4426950408889634f;  // gamma*log2(e)
    const float K2 = 2.0f * GL;

    const unsigned short* gA = Zf + (size_t)R * TILE * DIM;
    const unsigned short* gB = Zf + (size_t)C * TILE * DIM;

    // xn for row R, pre-scaled: ncx = -GL * |x|^2   (32 values/thread as 8 float4)
    f32x4 ncxv[8];
#pragma unroll
    for (int m = 0; m < 8; ++m) {
        f32x4 v = *(const f32x4*)&n2[R * TILE + wr * 128 + m * 16 + g * 4];
        ncxv[m] = v * (-GL);
    }

    // prologue: A panel (16 loads) + B chunk0 (2 loads)
    STAGE_A(gA);
    STB(gB, 0, 0);

    double dacc = 0.0;

    for (int L = start; L < end; ++L) {
        const bool lastT = (L == end - 1);
        // next tile coords (row-major triangle walk)
        int Rn = R, Cn = C + 1;
        if (Cn >= NB) { Rn = R + 1; Cn = Rn; }
        if (Rn > NB - 1) Rn = NB - 1;
        const unsigned short* gBn = Zf + (size_t)(Cn < NB ? Cn : NB - 1) * TILE * DIM;

        f32x4 acc[8][4];
#pragma unroll
        for (int m = 0; m < 8; ++m)
#pragma unroll
            for (int n = 0; n < 4; ++n) acc[m][n] = {0.f, 0.f, 0.f, 0.f};

#pragma unroll
        for (int ch = 0; ch < 8; ++ch) {
            if (ch < 7) {
                STB(gB, ch + 1, (ch + 1) & 1);
                asm volatile("s_waitcnt vmcnt(2)" ::: "memory");
            } else if (!lastT) {
                STB(gBn, 0, 0);  // buf parity continues: (7+1)&1 == 0
                asm volatile("s_waitcnt vmcnt(2)" ::: "memory");
            } else {
                asm volatile("s_waitcnt vmcnt(0)" ::: "memory");
            }
            __builtin_amdgcn_s_barrier();  // chunk-ch data resident for all waves

            const int pb = ch & 1;
            half8 bq[4];
#pragma unroll
            for (int n = 0; n < 4; ++n)
                bq[n] = *(const half8*)&lds[65536 + pb * 8192 + boff + n * 512];
            __builtin_amdgcn_s_setprio(1);
#pragma unroll
            for (int m = 0; m < 8; ++m) {
                half8 aq = *(const half8*)&lds[ch * 8192 + aoff + m * 512];
#pragma unroll
                for (int n = 0; n < 4; ++n)
                    acc[m][n] = __builtin_amdgcn_mfma_f32_16x16x32_f16(aq, bq[n], acc[m][n], 0, 0, 0);
            }
            __builtin_amdgcn_s_setprio(0);
            __builtin_amdgcn_s_barrier();  // all waves done reading before buf rewrite
        }

        // ---- epilogue (registers only; stages keep flying) ----
        float ncy[4];
#pragma unroll
        for (int n = 0; n < 4; ++n)
            ncy[n] = -GL * n2[C * TILE + wc * 64 + n * 16 + fr];

        if (R != C) {
            float fs0 = 0.f, fs1 = 0.f, fs2 = 0.f, fs3 = 0.f;
#pragma unroll
            for (int m = 0; m < 8; ++m) {
#pragma unroll
                for (int j = 0; j < 4; ++j) {
                    const float a = ncxv[m][j];
                    fs0 += __builtin_amdgcn_exp2f(fmaf(K2, acc[m][0][j], ncy[0]) + a);
                    fs1 += __builtin_amdgcn_exp2f(fmaf(K2, acc[m][1][j], ncy[1]) + a);
                    fs2 += __builtin_amdgcn_exp2f(fmaf(K2, acc[m][2][j], ncy[2]) + a);
                    fs3 += __builtin_amdgcn_exp2f(fmaf(K2, acc[m][3][j], ncy[3]) + a);
                }
            }
            const float sgn2 = ((R < 32) == (C < 32)) ? 2.0f : -2.0f;
            dacc += (double)(sgn2 * ((fs0 + fs1) + (fs2 + fs3)));
        } else {  // diagonal tile: i<j -> 2, i==j -> 1, i>j -> 0  (same half, sgn +1)
            float fsum = 0.f;
#pragma unroll
            for (int m = 0; m < 8; ++m) {
#pragma unroll
                for (int j = 0; j < 4; ++j) {
                    const int gi = R * TILE + wr * 128 + m * 16 + g * 4 + j;
#pragma unroll
                    for (int n = 0; n < 4; ++n) {
                        const int gj = C * TILE + wc * 64 + n * 16 + fr;
                        float e = __builtin_amdgcn_exp2f(fmaf(K2, acc[m][n][j], ncy[n]) + ncxv[m][j]);
                        float wgt = (gi < gj) ? 2.0f : ((gi == gj) ? 1.0f : 0.0f);
                        fsum += wgt * e;
                    }
                }
            }
            dacc += (double)fsum;
        }

        // advance; restage A + xn on row change (rare; covered by next vmcnt(2))
        if (!lastT) {
            if (Rn != R) {
                const unsigned short* gAn = Zf + (size_t)Rn * TILE * DIM;
                STAGE_A(gAn);
#pragma unroll
                for (int m = 0; m < 8; ++m) {
                    f32x4 v = *(const f32x4*)&n2[Rn * TILE + wr * 128 + m * 16 + g * 4];
                    ncxv[m] = v * (-GL);
                }
            }
            R = Rn; C = Cn; gB = gBn;
        }
    }

    // block reduce: per-thread double -> per-wave -> block
#pragma unroll
    for (int off = 32; off; off >>= 1) dacc += __shfl_xor(dacc, off);
    __syncthreads();
    double* wsum = (double*)&lds[0];
    if (l == 0) wsum[w] = dacc;
    __syncthreads();
    if (tid == 0) {
        double tot = 0.0;
#pragma unroll
        for (int i = 0; i < 8; ++i) tot += wsum[i];
        partial[blockIdx.x] = tot;
    }
}

// ---------------- final reduce: 256 doubles -> scalar ----------------
__global__ void reduce_partials_kernel(const double* __restrict__ partial,
                                       float* __restrict__ out) {
    __shared__ double ws[4];
    double s = (threadIdx.x < 256) ? partial[threadIdx.x] : 0.0;
#pragma unroll
    for (int off = 32; off; off >>= 1) s += __shfl_xor(s, off);
    if ((threadIdx.x & 63) == 0) ws[threadIdx.x >> 6] = s;
    __syncthreads();
    if (threadIdx.x == 0) {
        double tot = ws[0] + ws[1] + ws[2] + ws[3];
        out[0] = (float)(tot / ((double)NH * (double)NH));
    }
}

extern "C" void kernel_launch(void* const* d_in, const int* in_sizes, int n_in,
                              void* d_out, int out_size, void* d_ws, size_t ws_size,
                              hipStream_t stream) {
    const float* zs = (const float*)d_in[0];
    const float* zt = (const float*)d_in[1];
    float* out = (float*)d_out;

    unsigned short* Zf = (unsigned short*)d_ws;                  // 8 MB (f16)
    float*  n2      = (float*)((char*)d_ws + 8388608);           // 64 KB
    double* partial = (double*)((char*)d_ws + 8454144);          // 2 KB

    prep_kernel<<<NTOT / 4, 256, 0, stream>>>(zs, zt, Zf, n2);
    mmd_mfma_kernel<<<256, 512, 0, stream>>>(Zf, n2, partial);
    reduce_partials_kernel<<<1, 256, 0, stream>>>(partial, out);
}